// Round 18
// baseline (115.272 us; speedup 1.0000x reference)
//
#include <hip/hip_runtime.h>
#include <hip/hip_fp16.h>

typedef unsigned short ushort_t;
typedef unsigned int u32;
typedef short short8 __attribute__((ext_vector_type(8)));
typedef float f32x2 __attribute__((ext_vector_type(2)));
typedef float f32x4 __attribute__((ext_vector_type(4)));
typedef u32 u32x2 __attribute__((ext_vector_type(2)));
typedef u32 u32x4 __attribute__((ext_vector_type(4)));
typedef __fp16 h16x2 __attribute__((ext_vector_type(2)));
typedef _Float16 h16v8 __attribute__((ext_vector_type(8)));

#define N_PTS 100000
#define NSAMP 16
#define LOG2E 1.44269504088896340736f

__device__ __forceinline__ ushort_t f2h(float f) {
    __fp16 h = (__fp16)f; return __builtin_bit_cast(ushort_t, h);
}
__device__ __forceinline__ u32 pk2h(float lo, float hi) {        // v_cvt_pkrtz_f16_f32
    return __builtin_bit_cast(u32, __builtin_amdgcn_cvt_pkrtz(lo, hi));
}
__device__ __forceinline__ float h2f_lo(u32 p) { return __low2float(__builtin_bit_cast(__half2, p)); }
__device__ __forceinline__ float h2f_hi(u32 p) { return __high2float(__builtin_bit_cast(__half2, p)); }
__device__ __forceinline__ u32 hadd2u(u32 a, u32 b) {
    return __builtin_bit_cast(u32, __hadd2(__builtin_bit_cast(__half2, a), __builtin_bit_cast(__half2, b)));
}
__device__ __forceinline__ u32 hsub2u(u32 a, u32 b) {
    return __builtin_bit_cast(u32, __hsub2(__builtin_bit_cast(__half2, a), __builtin_bit_cast(__half2, b)));
}
__device__ __forceinline__ u32 hmul2u(u32 a, u32 b) {
    return __builtin_bit_cast(u32, __hmul2(__builtin_bit_cast(__half2, a), __builtin_bit_cast(__half2, b)));
}
__device__ __forceinline__ u32 hmax2u(u32 a, u32 b) {
    u32 r; asm("v_pk_max_f16 %0, %1, %2" : "=v"(r) : "v"(a), "v"(b)); return r;
}
__device__ __forceinline__ float rfl(float x) {                  // force SGPR
    return __builtin_bit_cast(float, (int)__builtin_amdgcn_readfirstlane(__builtin_bit_cast(int, x)));
}
__device__ __forceinline__ f32x4 mfma16(u32x4 a, short8 b, f32x4 c) {
    return __builtin_amdgcn_mfma_f32_16x16x32_f16(
        __builtin_bit_cast(h16v8, a), __builtin_bit_cast(h16v8, b), c, 0, 0, 0);
}

// ---------------------------------------------------------------------------
// Kernel A: qkv[i][0..63]=q, [64..127]=k', [128..191]=v   (f16 in workspace)
// k' = k + bk + bw  (bw = BN1 pre-scaled bias folded here).
// Grid 512. C-write via per-wave LDS transpose (r17-verified): fragments ->
// LDS tile (row stride 88 ushorts) -> 2x ds_read_b128 -> 2x coalesced
// global_store_dwordx4 per m-block.
// ---------------------------------------------------------------------------
__global__ __launch_bounds__(256, 4) void qkv_kernel(
    const float* __restrict__ feat,
    const float* __restrict__ Wq, const float* __restrict__ bq,
    const float* __restrict__ Wk, const float* __restrict__ bk,
    const float* __restrict__ Wv, const float* __restrict__ bv,
    const float* __restrict__ wg1, const float* __restrict__ wbe1,
    const float* __restrict__ wm1, const float* __restrict__ wv1,
    ushort_t* __restrict__ qkv)
{
    __shared__ ushort_t sl[4][16 * 88];   // per-wave transpose tile (2816 B)

    const int tid  = threadIdx.x;
    const int lane = tid & 63;
    const int wid  = tid >> 6;
    const int jl   = lane & 15;
    const int g    = lane >> 4;

    const float* Ws[3] = {Wq, Wk, Wv};
    const float* bs[3] = {bq, bk, bv};

    short8 bfrag[3][4][2];
    float  bias[3][4];
#pragma unroll
    for (int m = 0; m < 3; m++)
#pragma unroll
        for (int cb = 0; cb < 4; cb++) {
#pragma unroll
            for (int h = 0; h < 2; h++) {
                short8 f;
#pragma unroll
                for (int e = 0; e < 8; e++)
                    f[e] = (short)f2h(Ws[m][(h * 32 + g * 8 + e) * 64 + cb * 16 + jl]);
                bfrag[m][cb][h] = f;
            }
            const int c = cb * 16 + jl;
            float b = bs[m][c];
            if (m == 1) {      // fold BN1 pre-scaled bias into k
                const float s = wg1[c] * rsqrtf(wv1[c] + 1e-5f);   // >0
                b += wbe1[c] / s - wm1[c];
            }
            bias[m][cb] = b;
        }

    ushort_t* tw = sl[wid];

    const int nwaves = gridDim.x * (blockDim.x >> 6);
    const int gw     = blockIdx.x * (blockDim.x >> 6) + wid;
    const int ntiles = N_PTS / 16;   // 6250, exact

    for (int t = gw; t < ntiles; t += nwaves) {
        const int i0 = t * 16;
        const float* arow = feat + (i0 + jl) * 64;
        const f32x4 a00 = *(const f32x4*)(arow + g * 8);
        const f32x4 a01 = *(const f32x4*)(arow + g * 8 + 4);
        const f32x4 a10 = *(const f32x4*)(arow + 32 + g * 8);
        const f32x4 a11 = *(const f32x4*)(arow + 32 + g * 8 + 4);
        u32x4 ap0, ap1;
#pragma unroll
        for (int e = 0; e < 2; e++) {
            ap0[e]     = pk2h(a00[2 * e], a00[2 * e + 1]);
            ap0[2 + e] = pk2h(a01[2 * e], a01[2 * e + 1]);
            ap1[e]     = pk2h(a10[2 * e], a10[2 * e + 1]);
            ap1[2 + e] = pk2h(a11[2 * e], a11[2 * e + 1]);
        }
#pragma unroll
        for (int m = 0; m < 3; m++) {
#pragma unroll
            for (int cb = 0; cb < 4; cb++) {
                f32x4 acc = {0.f, 0.f, 0.f, 0.f};
                acc = mfma16(ap0, bfrag[m][cb][0], acc);
                acc = mfma16(ap1, bfrag[m][cb][1], acc);
#pragma unroll
                for (int r = 0; r < 4; r++)
                    tw[(g * 4 + r) * 88 + cb * 16 + jl] = f2h(acc[r] + bias[m][cb]);
            }
            __builtin_amdgcn_wave_barrier();
            const ushort_t* rrow = tw + jl * 88 + g * 16;
            const u32x4 d0 = *(const u32x4*)(rrow);
            const u32x4 d1 = *(const u32x4*)(rrow + 8);
            ushort_t* gp = qkv + (i0 + jl) * 192 + m * 64 + g * 16;
            *(u32x4*)(gp)     = d0;
            *(u32x4*)(gp + 8) = d1;
            __builtin_amdgcn_wave_barrier();
        }
    }
}

// ---------------------------------------------------------------------------
// Kernel B: fused attention, ONE WAVE PER BLOCK (r13/r17 verified optimum)
// + cross-iteration prefetch of the idx-independent loads (idx value,
// point[i'], fq row) — removes the idx->gather serial latency from the
// per-point critical path. The idx-dependent gathers stay in-iteration.
// Per wave: one point at a time; lane = (j = lane&15, g = lane>>4).
// ---------------------------------------------------------------------------
__global__ __launch_bounds__(64, 2) void attn_kernel(
    const float* __restrict__ point, const int* __restrict__ idx,
    const ushort_t* __restrict__ qkv,
    const float* pW1, const float* pb1, const float* pg1, const float* pbe1,
    const float* pm1, const float* pv1, const float* pW2, const float* pb2,
    const float* wg1, const float* wbe1, const float* wm1, const float* wv1,
    const float* wW1, const float* wb1, const float* wg2, const float* wbe2,
    const float* wm2, const float* wv2, const float* wW2, const float* wb2,
    float* __restrict__ out)
{
    __shared__ float lds[736];

    const int lane = threadIdx.x & 63;
    const int jl   = lane & 15;
    const int g    = lane >> 4;

    // --- runtime idx dtype probe: int64 iff the 16 odd int32 words are all 0 ---
    int zp = 0;
#pragma unroll
    for (int k = 0; k < 16; k++) zp |= idx[2 * k + 1];
    const bool idx64 = (zp == 0);

    // --- linear_p layer 1 (3x3 + BN folded), wave-uniform -> SGPR ---
    float A1s[3][3], c1[3];
#pragma unroll
    for (int u = 0; u < 3; u++) {
        const float s = pg1[u] * rsqrtf(pv1[u] + 1e-5f);
        c1[u] = rfl((pb1[u] - pm1[u]) * s + pbe1[u]);
#pragma unroll
        for (int t = 0; t < 3; t++) A1s[t][u] = rfl(pW1[t * 3 + u] * s);
    }
    // --- per-channel constants, packed f16 ---
    h16x2 w01[2][8], w2pb[2][8];
#pragma unroll
    for (int h = 0; h < 2; h++)
#pragma unroll
        for (int e = 0; e < 8; e++) {
            const int c = h * 32 + g * 8 + e;
            w01[h][e]  = __builtin_amdgcn_cvt_pkrtz(pW2[0 * 64 + c], pW2[1 * 64 + c]);
            w2pb[h][e] = __builtin_amdgcn_cvt_pkrtz(pW2[2 * 64 + c], pb2[c]);
        }
    // --- W1 B-frag with BN1 scale folded into rows (cols 8..15 zero) ---
    short8 w1f[2];
#pragma unroll
    for (int h = 0; h < 2; h++)
#pragma unroll
        for (int e = 0; e < 8; e++) {
            const int c = h * 32 + g * 8 + e;
            const float s = wg1[c] * rsqrtf(wv1[c] + 1e-5f);
            w1f[h][e] = (jl < 8) ? (short)f2h(wW1[c * 8 + jl] * s) : (short)0;
        }
    // --- BN2 folded: ur = relu(u + b2nd); s2 and log2(e) folded into W2 ---
    const float s2o  = (jl < 8) ? wg2[jl] * rsqrtf(wv2[jl] + 1e-5f) : 1.f;
    const float b2nd = (jl < 8) ? (wb1[jl] + wbe2[jl] / s2o - wm2[jl]) : 0.f;
    short8 w2f;
#pragma unroll
    for (int e = 0; e < 8; e++) {
        const float s2e = wg2[e] * rsqrtf(wv2[e] + 1e-5f);
        w2f[e] = (g == 0 && jl < 8) ? (short)f2h(wW2[e * 8 + jl] * s2e * LOG2E) : (short)0;
    }
    const float b2o = (jl < 8) ? wb2[jl] * LOG2E : 0.f;

    float* l12 = &lds[0];                  // 16 rows x 12 f32 (phase-shared)
    u32*   tlu = (u32*)&lds[192];          // 16 rows x 34 u32 (f16x2 tile)

    const int nwaves = gridDim.x;          // one wave per block
    const int gw     = blockIdx.x;

    const char* qb  = (const char*)qkv;
    const u32   gsl = (u32)g * 16u;

    // ---- prologue prefetch for first iteration (idx-independent set) ----
    int   nb_pf = 0;
    float px0_pf = 0.f, px1_pf = 0.f, px2_pf = 0.f;
    u32x4 fqp0_pf = {0u, 0u, 0u, 0u}, fqp1_pf = {0u, 0u, 0u, 0u};
    if (gw < N_PTS) {
        nb_pf  = idx64 ? idx[(gw * NSAMP + jl) * 2] : idx[gw * NSAMP + jl];
        px0_pf = point[gw * 3 + 0];
        px1_pf = point[gw * 3 + 1];
        px2_pf = point[gw * 3 + 2];
        const u32 iOff = (u32)gw * 384u + gsl;
        fqp0_pf = *(const u32x4*)(qb + iOff);
        fqp1_pf = *(const u32x4*)(qb + iOff + 64);
    }

    for (int i = gw; i < N_PTS; i += nwaves) {
        // consume prefetched values
        const int   nb  = nb_pf;
        const float px0 = px0_pf, px1 = px1_pf, px2 = px2_pf;
        const u32x4 fqp0 = fqp0_pf, fqp1 = fqp1_pf;

        // idx-dependent gathers for THIS point (issued immediately)
        const u32 nOff = (u32)nb * 384u + gsl;
        const float nx0 = point[nb * 3 + 0];
        const float nx1 = point[nb * 3 + 1];
        const float nx2 = point[nb * 3 + 2];
        const u32x4 gkp0 = *(const u32x4*)(qb + nOff + 128);
        const u32x4 gkp1 = *(const u32x4*)(qb + nOff + 192);
        const u32x4 gvp0 = *(const u32x4*)(qb + nOff + 256);
        const u32x4 gvp1 = *(const u32x4*)(qb + nOff + 320);

        // prefetch NEXT iteration's idx-independent loads (latency hides
        // under this point's compute)
        const int i_next = i + nwaves;
        if (i_next < N_PTS) {
            nb_pf  = idx64 ? idx[(i_next * NSAMP + jl) * 2] : idx[i_next * NSAMP + jl];
            px0_pf = point[i_next * 3 + 0];
            px1_pf = point[i_next * 3 + 1];
            px2_pf = point[i_next * 3 + 2];
            const u32 iOffN = (u32)i_next * 384u + gsl;
            fqp0_pf = *(const u32x4*)(qb + iOffN);
            fqp1_pf = *(const u32x4*)(qb + iOffN + 64);
        }

        // position-encoding MLP (f32), then pack pr to f16 pairs
        const float d0 = nx0 - px0, d1 = nx1 - px1, d2 = nx2 - px2;
        float y[3];
#pragma unroll
        for (int u = 0; u < 3; u++)
            y[u] = fmaxf(d0 * A1s[0][u] + d1 * A1s[1][u] + d2 * A1s[2][u] + c1[u], 0.f);
        const h16x2 y01h  = __builtin_amdgcn_cvt_pkrtz(y[0], y[1]);
        const h16x2 y2one = __builtin_amdgcn_cvt_pkrtz(y[2], 1.0f);
        u32 prp[2][4];
#pragma unroll
        for (int h = 0; h < 2; h++)
#pragma unroll
            for (int q = 0; q < 4; q++) {
                const float a0 = __builtin_amdgcn_fdot2(y01h, w01[h][2 * q],
                                   __builtin_amdgcn_fdot2(y2one, w2pb[h][2 * q], 0.f, false), false);
                const float a1 = __builtin_amdgcn_fdot2(y01h, w01[h][2 * q + 1],
                                   __builtin_amdgcn_fdot2(y2one, w2pb[h][2 * q + 1], 0.f, false), false);
                prp[h][q] = pk2h(a0, a1);
            }

        // wf = relu((gk' - fq) + pr) in packed f16 (bw lives in gk')
        u32x4 afp0, afp1;
#pragma unroll
        for (int q = 0; q < 4; q++) {
            afp0[q] = hmax2u(hadd2u(hsub2u(gkp0[q], fqp0[q]), prp[0][q]), 0u);
            afp1[q] = hmax2u(hadd2u(hsub2u(gkp1[q], fqp1[q]), prp[1][q]), 0u);
        }
        f32x4 u = {0.f, 0.f, 0.f, 0.f};
        u = mfma16(afp0, w1f[0], u);
        u = mfma16(afp1, w1f[1], u);

        // l1: relu(u + b2nd) -> C->A transpose via LDS (row pad 12)
        if (jl < 8) {
#pragma unroll
            for (int r = 0; r < 4; r++)
                l12[(g * 4 + r) * 12 + jl] = fmaxf(u[r] + b2nd, 0.f);
        }
        __builtin_amdgcn_wave_barrier();
        u32x4 aU = {0u, 0u, 0u, 0u};
        if (g == 0) {
            const f32x4 ua = *(const f32x4*)(l12 + jl * 12);
            const f32x4 ub = *(const f32x4*)(l12 + jl * 12 + 4);
            aU[0] = pk2h(ua[0], ua[1]);
            aU[1] = pk2h(ua[2], ua[3]);
            aU[2] = pk2h(ub[0], ub[1]);
            aU[3] = pk2h(ub[2], ub[3]);
        }
        __builtin_amdgcn_wave_barrier();
        f32x4 u2 = {0.f, 0.f, 0.f, 0.f};
        u2 = mfma16(aU, w2f, u2);

        // softmax over 16 neighbors in exp2 domain (log2e pre-folded)
        const float x0 = u2[0] + b2o, x1 = u2[1] + b2o, x2 = u2[2] + b2o, x3 = u2[3] + b2o;
        float m = fmaxf(fmaxf(x0, x1), fmaxf(x2, x3));
        m = fmaxf(m, __shfl_xor(m, 16, 64));
        m = fmaxf(m, __shfl_xor(m, 32, 64));
        const float e0 = exp2f(x0 - m), e1 = exp2f(x1 - m);
        const float e2 = exp2f(x2 - m), e3 = exp2f(x3 - m);
        float ssum = e0 + e1 + e2 + e3;
        ssum += __shfl_xor(ssum, 16, 64);
        ssum += __shfl_xor(ssum, 32, 64);
        const float inv = 1.0f / ssum;

        // l2 (same region): w[j][o'] rows pad 12
        if (jl < 8) {
            l12[(g * 4 + 0) * 12 + jl] = e0 * inv;
            l12[(g * 4 + 1) * 12 + jl] = e1 * inv;
            l12[(g * 4 + 2) * 12 + jl] = e2 * inv;
            l12[(g * 4 + 3) * 12 + jl] = e3 * inv;
        }
        __builtin_amdgcn_wave_barrier();
        const f32x4 wa  = *(const f32x4*)(l12 + jl * 12);      // w[j][0..3]
        const f32x4 wbv = *(const f32x4*)(l12 + jl * 12 + 4);  // w[j][4..7]
        __builtin_amdgcn_wave_barrier();
        u32 wh[4];
        wh[0] = pk2h(wa[0], wa[1]);
        wh[1] = pk2h(wa[2], wa[3]);
        wh[2] = pk2h(wbv[0], wbv[1]);
        wh[3] = pk2h(wbv[2], wbv[3]);

        // products p[j][cp] = (gv + pr) * w  in packed f16 -> tile (stride 34)
        u32* trow = tlu + jl * 34 + g * 4;
        u32x2 p00, p01, p10, p11;
        p00[0] = hmul2u(hadd2u(gvp0[0], prp[0][0]), wh[0]);
        p00[1] = hmul2u(hadd2u(gvp0[1], prp[0][1]), wh[1]);
        p01[0] = hmul2u(hadd2u(gvp0[2], prp[0][2]), wh[2]);
        p01[1] = hmul2u(hadd2u(gvp0[3], prp[0][3]), wh[3]);
        p10[0] = hmul2u(hadd2u(gvp1[0], prp[1][0]), wh[0]);
        p10[1] = hmul2u(hadd2u(gvp1[1], prp[1][1]), wh[1]);
        p11[0] = hmul2u(hadd2u(gvp1[2], prp[1][2]), wh[2]);
        p11[1] = hmul2u(hadd2u(gvp1[3], prp[1][3]), wh[3]);
        *(u32x2*)(trow + 0)  = p00;
        *(u32x2*)(trow + 2)  = p01;
        *(u32x2*)(trow + 16) = p10;
        *(u32x2*)(trow + 18) = p11;
        __builtin_amdgcn_wave_barrier();

        // reduction: half-wave (lane>>5) sums rows 0..7 / 8..15 of channel
        // pair cp = lane&31; combine with one xor32 shuffle.
        const u32* tb = tlu + (lane & 31);
        const int rbase = (lane >> 5) * 8;
        u32 v[8];
#pragma unroll
        for (int j = 0; j < 8; j++) v[j] = tb[(rbase + j) * 34];
#pragma unroll
        for (int s = 4; s >= 1; s >>= 1)
#pragma unroll
            for (int j = 0; j < s; j++) v[j] = hadd2u(v[j], v[j + s]);
        const u32 o32 = (u32)__shfl_xor((int)v[0], 32, 64);
        const u32 tot = hadd2u(v[0], o32);
        if (lane < 32) {
            f32x2 o;
            o[0] = h2f_lo(tot);
            o[1] = h2f_hi(tot);
            *(f32x2*)(out + i * 64 + 2 * lane) = o;
        }
    }
}

extern "C" void kernel_launch(void* const* d_in, const int* in_sizes, int n_in,
                              void* d_out, int out_size, void* d_ws, size_t ws_size,
                              hipStream_t stream) {
    const float* point = (const float*)d_in[0];
    const float* feat  = (const float*)d_in[1];
    const int*   idx   = (const int*)d_in[2];
    const float* Wq = (const float*)d_in[3];  const float* bq = (const float*)d_in[4];
    const float* Wk = (const float*)d_in[5];  const float* bk = (const float*)d_in[6];
    const float* Wv = (const float*)d_in[7];  const float* bv = (const float*)d_in[8];
    const float* pW1  = (const float*)d_in[9];
    const float* pb1  = (const float*)d_in[10];
    const float* pg1  = (const float*)d_in[11];
    const float* pbe1 = (const float*)d_in[12];
    const float* pm1  = (const float*)d_in[13];
    const float* pv1  = (const float*)d_in[14];
    const float* pW2  = (const float*)d_in[15];
    const float* pb2  = (const float*)d_in[16];
    const float* wg1  = (const float*)d_in[17];
    const float* wbe1 = (const float*)d_in[18];
    const float* wm1  = (const float*)d_in[19];
    const float* wv1  = (const float*)d_in[20];
    const float* wW1  = (const float*)d_in[21];
    const float* wb1  = (const float*)d_in[22];
    const float* wg2  = (const float*)d_in[23];
    const float* wbe2 = (const float*)d_in[24];
    const float* wm2  = (const float*)d_in[25];
    const float* wv2  = (const float*)d_in[26];
    const float* wW2  = (const float*)d_in[27];
    const float* wb2  = (const float*)d_in[28];

    ushort_t* qkv  = (ushort_t*)d_ws;            // 100000*192*2B = 38.4 MB (f16)
    float*    outp = (float*)d_out;

    hipLaunchKernelGGL(qkv_kernel, dim3(512), dim3(256), 0, stream,
                       feat, Wq, bq, Wk, bk, Wv, bv,
                       wg1, wbe1, wm1, wv1, qkv);
    hipLaunchKernelGGL(attn_kernel, dim3(8192), dim3(64), 0, stream,
                       point, idx, qkv,
                       pW1, pb1, pg1, pbe1, pm1, pv1, pW2, pb2,
                       wg1, wbe1, wm1, wv1, wW1, wb1,
                       wg2, wbe2, wm2, wv2, wW2, wb2,
                       outp);
}

// Round 19
// 112.845 us; speedup vs baseline: 1.0215x; 1.0215x over previous
//
#include <hip/hip_runtime.h>
#include <hip/hip_fp16.h>

typedef unsigned short ushort_t;
typedef unsigned int u32;
typedef short short8 __attribute__((ext_vector_type(8)));
typedef float f32x2 __attribute__((ext_vector_type(2)));
typedef float f32x4 __attribute__((ext_vector_type(4)));
typedef u32 u32x2 __attribute__((ext_vector_type(2)));
typedef u32 u32x4 __attribute__((ext_vector_type(4)));
typedef __fp16 h16x2 __attribute__((ext_vector_type(2)));
typedef _Float16 h16v8 __attribute__((ext_vector_type(8)));

#define N_PTS 100000
#define NSAMP 16
#define LOG2E 1.44269504088896340736f

__device__ __forceinline__ ushort_t f2h(float f) {
    __fp16 h = (__fp16)f; return __builtin_bit_cast(ushort_t, h);
}
__device__ __forceinline__ u32 pk2h(float lo, float hi) {        // v_cvt_pkrtz_f16_f32
    return __builtin_bit_cast(u32, __builtin_amdgcn_cvt_pkrtz(lo, hi));
}
__device__ __forceinline__ float h2f_lo(u32 p) { return __low2float(__builtin_bit_cast(__half2, p)); }
__device__ __forceinline__ float h2f_hi(u32 p) { return __high2float(__builtin_bit_cast(__half2, p)); }
__device__ __forceinline__ u32 hadd2u(u32 a, u32 b) {
    return __builtin_bit_cast(u32, __hadd2(__builtin_bit_cast(__half2, a), __builtin_bit_cast(__half2, b)));
}
__device__ __forceinline__ u32 hsub2u(u32 a, u32 b) {
    return __builtin_bit_cast(u32, __hsub2(__builtin_bit_cast(__half2, a), __builtin_bit_cast(__half2, b)));
}
__device__ __forceinline__ u32 hmul2u(u32 a, u32 b) {
    return __builtin_bit_cast(u32, __hmul2(__builtin_bit_cast(__half2, a), __builtin_bit_cast(__half2, b)));
}
__device__ __forceinline__ u32 hmax2u(u32 a, u32 b) {
    u32 r; asm("v_pk_max_f16 %0, %1, %2" : "=v"(r) : "v"(a), "v"(b)); return r;
}
__device__ __forceinline__ float rfl(float x) {                  // force SGPR
    return __builtin_bit_cast(float, (int)__builtin_amdgcn_readfirstlane(__builtin_bit_cast(int, x)));
}
__device__ __forceinline__ f32x4 mfma16(u32x4 a, short8 b, f32x4 c) {
    return __builtin_amdgcn_mfma_f32_16x16x32_f16(
        __builtin_bit_cast(h16v8, a), __builtin_bit_cast(h16v8, b), c, 0, 0, 0);
}

// ---------------------------------------------------------------------------
// Kernel A: qkv[i][0..63]=q, [64..127]=k', [128..191]=v   (f16 in workspace)
// k' = k + bk + bw  (bw = BN1 pre-scaled bias folded here).
// Grid 512. C-write via per-wave LDS transpose (r17-verified): fragments ->
// LDS tile (row stride 88 ushorts) -> 2x ds_read_b128 -> 2x coalesced
// global_store_dwordx4 per m-block.
// ---------------------------------------------------------------------------
__global__ __launch_bounds__(256, 4) void qkv_kernel(
    const float* __restrict__ feat,
    const float* __restrict__ Wq, const float* __restrict__ bq,
    const float* __restrict__ Wk, const float* __restrict__ bk,
    const float* __restrict__ Wv, const float* __restrict__ bv,
    const float* __restrict__ wg1, const float* __restrict__ wbe1,
    const float* __restrict__ wm1, const float* __restrict__ wv1,
    ushort_t* __restrict__ qkv)
{
    __shared__ ushort_t sl[4][16 * 88];   // per-wave transpose tile (2816 B)

    const int tid  = threadIdx.x;
    const int lane = tid & 63;
    const int wid  = tid >> 6;
    const int jl   = lane & 15;
    const int g    = lane >> 4;

    const float* Ws[3] = {Wq, Wk, Wv};
    const float* bs[3] = {bq, bk, bv};

    short8 bfrag[3][4][2];
    float  bias[3][4];
#pragma unroll
    for (int m = 0; m < 3; m++)
#pragma unroll
        for (int cb = 0; cb < 4; cb++) {
#pragma unroll
            for (int h = 0; h < 2; h++) {
                short8 f;
#pragma unroll
                for (int e = 0; e < 8; e++)
                    f[e] = (short)f2h(Ws[m][(h * 32 + g * 8 + e) * 64 + cb * 16 + jl]);
                bfrag[m][cb][h] = f;
            }
            const int c = cb * 16 + jl;
            float b = bs[m][c];
            if (m == 1) {      // fold BN1 pre-scaled bias into k
                const float s = wg1[c] * rsqrtf(wv1[c] + 1e-5f);   // >0
                b += wbe1[c] / s - wm1[c];
            }
            bias[m][cb] = b;
        }

    ushort_t* tw = sl[wid];

    const int nwaves = gridDim.x * (blockDim.x >> 6);
    const int gw     = blockIdx.x * (blockDim.x >> 6) + wid;
    const int ntiles = N_PTS / 16;   // 6250, exact

    for (int t = gw; t < ntiles; t += nwaves) {
        const int i0 = t * 16;
        const float* arow = feat + (i0 + jl) * 64;
        const f32x4 a00 = *(const f32x4*)(arow + g * 8);
        const f32x4 a01 = *(const f32x4*)(arow + g * 8 + 4);
        const f32x4 a10 = *(const f32x4*)(arow + 32 + g * 8);
        const f32x4 a11 = *(const f32x4*)(arow + 32 + g * 8 + 4);
        u32x4 ap0, ap1;
#pragma unroll
        for (int e = 0; e < 2; e++) {
            ap0[e]     = pk2h(a00[2 * e], a00[2 * e + 1]);
            ap0[2 + e] = pk2h(a01[2 * e], a01[2 * e + 1]);
            ap1[e]     = pk2h(a10[2 * e], a10[2 * e + 1]);
            ap1[2 + e] = pk2h(a11[2 * e], a11[2 * e + 1]);
        }
#pragma unroll
        for (int m = 0; m < 3; m++) {
#pragma unroll
            for (int cb = 0; cb < 4; cb++) {
                f32x4 acc = {0.f, 0.f, 0.f, 0.f};
                acc = mfma16(ap0, bfrag[m][cb][0], acc);
                acc = mfma16(ap1, bfrag[m][cb][1], acc);
#pragma unroll
                for (int r = 0; r < 4; r++)
                    tw[(g * 4 + r) * 88 + cb * 16 + jl] = f2h(acc[r] + bias[m][cb]);
            }
            __builtin_amdgcn_wave_barrier();
            const ushort_t* rrow = tw + jl * 88 + g * 16;
            const u32x4 d0 = *(const u32x4*)(rrow);
            const u32x4 d1 = *(const u32x4*)(rrow + 8);
            ushort_t* gp = qkv + (i0 + jl) * 192 + m * 64 + g * 16;
            *(u32x4*)(gp)     = d0;
            *(u32x4*)(gp + 8) = d1;
            __builtin_amdgcn_wave_barrier();
        }
    }
}

// ---------------------------------------------------------------------------
// Kernel B: fused attention, ONE WAVE PER BLOCK (r13/r17 verified optimum:
// VGPR 56, occ 38%, no spill; 2-wave blocks and forced caps both regress;
// cross-iteration prefetch regresses — compiler already hoists).
// Per wave: one point at a time; lane = (j = lane&15, g = lane>>4).
// wf in packed f16 -> A-frag directly. Products packed f16 -> f16x2 LDS tile
// (stride 34); reduction split across half-waves + xor32 combine.
// Per-wave LDS (f32 units): [0,192) l1/l2 shared (16x12), [192,736) tile.
// ---------------------------------------------------------------------------
__global__ __launch_bounds__(64, 2) void attn_kernel(
    const float* __restrict__ point, const int* __restrict__ idx,
    const ushort_t* __restrict__ qkv,
    const float* pW1, const float* pb1, const float* pg1, const float* pbe1,
    const float* pm1, const float* pv1, const float* pW2, const float* pb2,
    const float* wg1, const float* wbe1, const float* wm1, const float* wv1,
    const float* wW1, const float* wb1, const float* wg2, const float* wbe2,
    const float* wm2, const float* wv2, const float* wW2, const float* wb2,
    float* __restrict__ out)
{
    __shared__ float lds[736];

    const int lane = threadIdx.x & 63;
    const int jl   = lane & 15;
    const int g    = lane >> 4;

    // --- runtime idx dtype probe: int64 iff the 16 odd int32 words are all 0 ---
    int zp = 0;
#pragma unroll
    for (int k = 0; k < 16; k++) zp |= idx[2 * k + 1];
    const bool idx64 = (zp == 0);

    // --- linear_p layer 1 (3x3 + BN folded), wave-uniform -> SGPR ---
    float A1s[3][3], c1[3];
#pragma unroll
    for (int u = 0; u < 3; u++) {
        const float s = pg1[u] * rsqrtf(pv1[u] + 1e-5f);
        c1[u] = rfl((pb1[u] - pm1[u]) * s + pbe1[u]);
#pragma unroll
        for (int t = 0; t < 3; t++) A1s[t][u] = rfl(pW1[t * 3 + u] * s);
    }
    // --- per-channel constants, packed f16: w01 = {W[0][c],W[1][c]},
    //     w2pb = {W[2][c], pb2[c]} (consumed via fdot2 with {y2, 1}) ---
    h16x2 w01[2][8], w2pb[2][8];
#pragma unroll
    for (int h = 0; h < 2; h++)
#pragma unroll
        for (int e = 0; e < 8; e++) {
            const int c = h * 32 + g * 8 + e;
            w01[h][e]  = __builtin_amdgcn_cvt_pkrtz(pW2[0 * 64 + c], pW2[1 * 64 + c]);
            w2pb[h][e] = __builtin_amdgcn_cvt_pkrtz(pW2[2 * 64 + c], pb2[c]);
        }
    // --- W1 B-frag with BN1 scale folded into rows (cols 8..15 zero) ---
    short8 w1f[2];
#pragma unroll
    for (int h = 0; h < 2; h++)
#pragma unroll
        for (int e = 0; e < 8; e++) {
            const int c = h * 32 + g * 8 + e;
            const float s = wg1[c] * rsqrtf(wv1[c] + 1e-5f);
            w1f[h][e] = (jl < 8) ? (short)f2h(wW1[c * 8 + jl] * s) : (short)0;
        }
    // --- BN2 folded: ur = relu(u + b2nd); s2 and log2(e) folded into W2 ---
    const float s2o  = (jl < 8) ? wg2[jl] * rsqrtf(wv2[jl] + 1e-5f) : 1.f;
    const float b2nd = (jl < 8) ? (wb1[jl] + wbe2[jl] / s2o - wm2[jl]) : 0.f;
    short8 w2f;
#pragma unroll
    for (int e = 0; e < 8; e++) {
        const float s2e = wg2[e] * rsqrtf(wv2[e] + 1e-5f);
        w2f[e] = (g == 0 && jl < 8) ? (short)f2h(wW2[e * 8 + jl] * s2e * LOG2E) : (short)0;
    }
    const float b2o = (jl < 8) ? wb2[jl] * LOG2E : 0.f;

    float* l12 = &lds[0];                  // 16 rows x 12 f32 (phase-shared)
    u32*   tlu = (u32*)&lds[192];          // 16 rows x 34 u32 (f16x2 tile)

    const int nwaves = gridDim.x;          // one wave per block
    const int gw     = blockIdx.x;

    const char* qb  = (const char*)qkv;
    const u32   gsl = (u32)g * 16u;

    for (int i = gw; i < N_PTS; i += nwaves) {
        const int nb = idx64 ? idx[(i * NSAMP + jl) * 2] : idx[i * NSAMP + jl];

        const u32 iOff = (u32)i * 384u + gsl;
        const u32 nOff = (u32)nb * 384u + gsl;

        const float px0 = point[i * 3 + 0];
        const float px1 = point[i * 3 + 1];
        const float px2 = point[i * 3 + 2];
        const float nx0 = point[nb * 3 + 0];
        const float nx1 = point[nb * 3 + 1];
        const float nx2 = point[nb * 3 + 2];
        const u32x4 fqp0 = *(const u32x4*)(qb + iOff);
        const u32x4 fqp1 = *(const u32x4*)(qb + iOff + 64);
        const u32x4 gkp0 = *(const u32x4*)(qb + nOff + 128);
        const u32x4 gkp1 = *(const u32x4*)(qb + nOff + 192);
        const u32x4 gvp0 = *(const u32x4*)(qb + nOff + 256);
        const u32x4 gvp1 = *(const u32x4*)(qb + nOff + 320);

        // position-encoding MLP (f32), then pack pr to f16 pairs
        const float d0 = nx0 - px0, d1 = nx1 - px1, d2 = nx2 - px2;
        float y[3];
#pragma unroll
        for (int u = 0; u < 3; u++)
            y[u] = fmaxf(d0 * A1s[0][u] + d1 * A1s[1][u] + d2 * A1s[2][u] + c1[u], 0.f);
        const h16x2 y01h  = __builtin_amdgcn_cvt_pkrtz(y[0], y[1]);
        const h16x2 y2one = __builtin_amdgcn_cvt_pkrtz(y[2], 1.0f);
        u32 prp[2][4];
#pragma unroll
        for (int h = 0; h < 2; h++)
#pragma unroll
            for (int q = 0; q < 4; q++) {
                const float a0 = __builtin_amdgcn_fdot2(y01h, w01[h][2 * q],
                                   __builtin_amdgcn_fdot2(y2one, w2pb[h][2 * q], 0.f, false), false);
                const float a1 = __builtin_amdgcn_fdot2(y01h, w01[h][2 * q + 1],
                                   __builtin_amdgcn_fdot2(y2one, w2pb[h][2 * q + 1], 0.f, false), false);
                prp[h][q] = pk2h(a0, a1);
            }

        // wf = relu((gk' - fq) + pr) in packed f16 (bw lives in gk')
        u32x4 afp0, afp1;
#pragma unroll
        for (int q = 0; q < 4; q++) {
            afp0[q] = hmax2u(hadd2u(hsub2u(gkp0[q], fqp0[q]), prp[0][q]), 0u);
            afp1[q] = hmax2u(hadd2u(hsub2u(gkp1[q], fqp1[q]), prp[1][q]), 0u);
        }
        f32x4 u = {0.f, 0.f, 0.f, 0.f};
        u = mfma16(afp0, w1f[0], u);
        u = mfma16(afp1, w1f[1], u);

        // l1: relu(u + b2nd) -> C->A transpose via LDS (row pad 12)
        if (jl < 8) {
#pragma unroll
            for (int r = 0; r < 4; r++)
                l12[(g * 4 + r) * 12 + jl] = fmaxf(u[r] + b2nd, 0.f);
        }
        __builtin_amdgcn_wave_barrier();
        u32x4 aU = {0u, 0u, 0u, 0u};
        if (g == 0) {
            const f32x4 ua = *(const f32x4*)(l12 + jl * 12);
            const f32x4 ub = *(const f32x4*)(l12 + jl * 12 + 4);
            aU[0] = pk2h(ua[0], ua[1]);
            aU[1] = pk2h(ua[2], ua[3]);
            aU[2] = pk2h(ub[0], ub[1]);
            aU[3] = pk2h(ub[2], ub[3]);
        }
        __builtin_amdgcn_wave_barrier();
        f32x4 u2 = {0.f, 0.f, 0.f, 0.f};
        u2 = mfma16(aU, w2f, u2);

        // softmax over 16 neighbors in exp2 domain (log2e pre-folded)
        const float x0 = u2[0] + b2o, x1 = u2[1] + b2o, x2 = u2[2] + b2o, x3 = u2[3] + b2o;
        float m = fmaxf(fmaxf(x0, x1), fmaxf(x2, x3));
        m = fmaxf(m, __shfl_xor(m, 16, 64));
        m = fmaxf(m, __shfl_xor(m, 32, 64));
        const float e0 = exp2f(x0 - m), e1 = exp2f(x1 - m);
        const float e2 = exp2f(x2 - m), e3 = exp2f(x3 - m);
        float ssum = e0 + e1 + e2 + e3;
        ssum += __shfl_xor(ssum, 16, 64);
        ssum += __shfl_xor(ssum, 32, 64);
        const float inv = 1.0f / ssum;

        // l2 (same region): w[j][o'] rows pad 12
        if (jl < 8) {
            l12[(g * 4 + 0) * 12 + jl] = e0 * inv;
            l12[(g * 4 + 1) * 12 + jl] = e1 * inv;
            l12[(g * 4 + 2) * 12 + jl] = e2 * inv;
            l12[(g * 4 + 3) * 12 + jl] = e3 * inv;
        }
        __builtin_amdgcn_wave_barrier();
        const f32x4 wa  = *(const f32x4*)(l12 + jl * 12);      // w[j][0..3]
        const f32x4 wbv = *(const f32x4*)(l12 + jl * 12 + 4);  // w[j][4..7]
        __builtin_amdgcn_wave_barrier();
        u32 wh[4];
        wh[0] = pk2h(wa[0], wa[1]);
        wh[1] = pk2h(wa[2], wa[3]);
        wh[2] = pk2h(wbv[0], wbv[1]);
        wh[3] = pk2h(wbv[2], wbv[3]);

        // products p[j][cp] = (gv + pr) * w  in packed f16 -> tile (stride 34)
        u32* trow = tlu + jl * 34 + g * 4;
        u32x2 p00, p01, p10, p11;
        p00[0] = hmul2u(hadd2u(gvp0[0], prp[0][0]), wh[0]);
        p00[1] = hmul2u(hadd2u(gvp0[1], prp[0][1]), wh[1]);
        p01[0] = hmul2u(hadd2u(gvp0[2], prp[0][2]), wh[2]);
        p01[1] = hmul2u(hadd2u(gvp0[3], prp[0][3]), wh[3]);
        p10[0] = hmul2u(hadd2u(gvp1[0], prp[1][0]), wh[0]);
        p10[1] = hmul2u(hadd2u(gvp1[1], prp[1][1]), wh[1]);
        p11[0] = hmul2u(hadd2u(gvp1[2], prp[1][2]), wh[2]);
        p11[1] = hmul2u(hadd2u(gvp1[3], prp[1][3]), wh[3]);
        *(u32x2*)(trow + 0)  = p00;
        *(u32x2*)(trow + 2)  = p01;
        *(u32x2*)(trow + 16) = p10;
        *(u32x2*)(trow + 18) = p11;
        __builtin_amdgcn_wave_barrier();

        // reduction: half-wave (lane>>5) sums rows 0..7 / 8..15 of channel
        // pair cp = lane&31; combine with one xor32 shuffle.
        const u32* tb = tlu + (lane & 31);
        const int rbase = (lane >> 5) * 8;
        u32 v[8];
#pragma unroll
        for (int j = 0; j < 8; j++) v[j] = tb[(rbase + j) * 34];
#pragma unroll
        for (int s = 4; s >= 1; s >>= 1)
#pragma unroll
            for (int j = 0; j < s; j++) v[j] = hadd2u(v[j], v[j + s]);
        const u32 o32 = (u32)__shfl_xor((int)v[0], 32, 64);
        const u32 tot = hadd2u(v[0], o32);
        if (lane < 32) {
            f32x2 o;
            o[0] = h2f_lo(tot);
            o[1] = h2f_hi(tot);
            *(f32x2*)(out + i * 64 + 2 * lane) = o;
        }
    }
}

extern "C" void kernel_launch(void* const* d_in, const int* in_sizes, int n_in,
                              void* d_out, int out_size, void* d_ws, size_t ws_size,
                              hipStream_t stream) {
    const float* point = (const float*)d_in[0];
    const float* feat  = (const float*)d_in[1];
    const int*   idx   = (const int*)d_in[2];
    const float* Wq = (const float*)d_in[3];  const float* bq = (const float*)d_in[4];
    const float* Wk = (const float*)d_in[5];  const float* bk = (const float*)d_in[6];
    const float* Wv = (const float*)d_in[7];  const float* bv = (const float*)d_in[8];
    const float* pW1  = (const float*)d_in[9];
    const float* pb1  = (const float*)d_in[10];
    const float* pg1  = (const float*)d_in[11];
    const float* pbe1 = (const float*)d_in[12];
    const float* pm1  = (const float*)d_in[13];
    const float* pv1  = (const float*)d_in[14];
    const float* pW2  = (const float*)d_in[15];
    const float* pb2  = (const float*)d_in[16];
    const float* wg1  = (const float*)d_in[17];
    const float* wbe1 = (const float*)d_in[18];
    const float* wm1  = (const float*)d_in[19];
    const float* wv1  = (const float*)d_in[20];
    const float* wW1  = (const float*)d_in[21];
    const float* wb1  = (const float*)d_in[22];
    const float* wg2  = (const float*)d_in[23];
    const float* wbe2 = (const float*)d_in[24];
    const float* wm2  = (const float*)d_in[25];
    const float* wv2  = (const float*)d_in[26];
    const float* wW2  = (const float*)d_in[27];
    const float* wb2  = (const float*)d_in[28];

    ushort_t* qkv  = (ushort_t*)d_ws;            // 100000*192*2B = 38.4 MB (f16)
    float*    outp = (float*)d_out;

    hipLaunchKernelGGL(qkv_kernel, dim3(512), dim3(256), 0, stream,
                       feat, Wq, bq, Wk, bk, Wv, bv,
                       wg1, wbe1, wm1, wv1, qkv);
    hipLaunchKernelGGL(attn_kernel, dim3(8192), dim3(64), 0, stream,
                       point, idx, qkv,
                       pW1, pb1, pg1, pbe1, pm1, pv1, pW2, pb2,
                       wg1, wbe1, wm1, wv1, wW1, wb1,
                       wg2, wbe2, wm2, wv2, wW2, wb2,
                       outp);
}